// Round 4
// baseline (3717.483 us; speedup 1.0000x reference)
//
#include <hip/hip_runtime.h>
#include <hip/hip_bf16.h>

#define T_LEN 256
#define B_DIM 128
#define I_DIM 256
#define H_DIM 1024

typedef __attribute__((ext_vector_type(8))) short short8;
typedef __attribute__((ext_vector_type(4))) float f32x4;

// Per-cluster barrier counters (4 batch-quarter clusters, 128B apart).
// Monotonic within a call; re-zeroed by init_hT0 every call/replay.
__device__ unsigned g_bar[4][32];

// RNE float->bf16 (self-contained; inputs here are never NaN)
static __device__ __forceinline__ unsigned short f2bf(float f) {
  unsigned u = __float_as_uint(f);
  return (unsigned short)((u + 0x7fffu + ((u >> 16) & 1u)) >> 16);
}

// ---------------------------------------------------------------------------
// Phase 1: x_proj GEMM (fp32, unchanged).
// ---------------------------------------------------------------------------
__global__ __launch_bounds__(256) void xproj_gemm(
    const float* __restrict__ A, const float* __restrict__ W,
    const float* __restrict__ bias, float* __restrict__ C) {
  __shared__ float As[64][33];
  __shared__ float Ws[64][33];

  const int tid = threadIdx.x;
  const int m0 = blockIdx.y * 64;
  const int n0 = blockIdx.x * 64;
  const int ty = tid >> 4;
  const int tx = tid & 15;
  const int r   = tid >> 3;
  const int c4  = (tid & 7) << 2;

  float acc[4][4] = {};

  for (int kc = 0; kc < I_DIM; kc += 32) {
#pragma unroll
    for (int p = 0; p < 2; ++p) {
      const int rr = r + p * 32;
      const float4 a = *(const float4*)(A + (size_t)(m0 + rr) * I_DIM + kc + c4);
      As[rr][c4 + 0] = a.x; As[rr][c4 + 1] = a.y;
      As[rr][c4 + 2] = a.z; As[rr][c4 + 3] = a.w;
      const float4 w = *(const float4*)(W + (size_t)(n0 + rr) * I_DIM + kc + c4);
      Ws[rr][c4 + 0] = w.x; Ws[rr][c4 + 1] = w.y;
      Ws[rr][c4 + 2] = w.z; Ws[rr][c4 + 3] = w.w;
    }
    __syncthreads();
#pragma unroll
    for (int k = 0; k < 32; ++k) {
      float av[4], wv[4];
#pragma unroll
      for (int i = 0; i < 4; ++i) av[i] = As[ty * 4 + i][k];
#pragma unroll
      for (int j = 0; j < 4; ++j) wv[j] = Ws[tx * 4 + j][k];
#pragma unroll
      for (int i = 0; i < 4; ++i)
#pragma unroll
        for (int j = 0; j < 4; ++j)
          acc[i][j] = fmaf(av[i], wv[j], acc[i][j]);
    }
    __syncthreads();
  }

  const float4 bv = *(const float4*)(bias + n0 + tx * 4);
#pragma unroll
  for (int i = 0; i < 4; ++i) {
    float4 o;
    o.x = acc[i][0] + bv.x;
    o.y = acc[i][1] + bv.y;
    o.z = acc[i][2] + bv.z;
    o.w = acc[i][3] + bv.w;
    *(float4*)(C + (size_t)(m0 + ty * 4 + i) * H_DIM + n0 + tx * 4) = o;
  }
}

// ---------------------------------------------------------------------------
// One-time converts: W_hh -> bf16 [j][k]; hT0 -> bf16 [b][k] broadcast of h0.
// init_hT0 also re-zeroes the persistent-kernel barrier counters.
// ---------------------------------------------------------------------------
__global__ __launch_bounds__(256) void cvt_w_bf16(
    const float* __restrict__ W, unsigned short* __restrict__ Wb) {
  const int i4 = blockIdx.x * 256 + threadIdx.x;     // one float4 per thread
  const float4 w = ((const float4*)W)[i4];
  ushort4 o;
  o.x = f2bf(w.x); o.y = f2bf(w.y); o.z = f2bf(w.z); o.w = f2bf(w.w);
  ((ushort4*)Wb)[i4] = o;
}

__global__ __launch_bounds__(256) void init_hT0(
    const float* __restrict__ h0, unsigned short* __restrict__ hT) {
  const int idx = blockIdx.x * 256 + threadIdx.x;    // [0, 131072)
  hT[idx] = f2bf(h0[idx & (H_DIM - 1)]);
  if (blockIdx.x == 0 && threadIdx.x < 128)
    ((unsigned*)g_bar)[threadIdx.x] = 0u;
}

// ---------------------------------------------------------------------------
// Phase 2: persistent cooperative kernel — whole time loop in ONE dispatch.
// Grid 256 = 64 j-tiles x 4 b-quarter clusters. Block 256 thr = 4 waves.
//
// Coherence protocol (round-4: NO per-step cache maintenance at all):
//  - The ONLY cross-block data per step are hT and the counter. Both are
//    accessed with explicit sc0 sc1 (L1+L2-bypass) instructions, coherent at
//    the L3 point by construction:
//      * h stores: relaxed agent atomic (write-through).
//      * h loads:  inline-asm global_load_dwordx4 sc0 sc1 (round-3's proven
//        spin mechanism, applied to data).
//      * counter:  RELEASE fetch_add (flushes any dirty L2 before bump) +
//        sc0 sc1 spin loads.
//  - NO buffer_inv per step (round-3's fence(acquire) nuked L1+L2 every step
//    -> W/x_proj/bias refetched from L3 each step = 396 MB FETCH, 9.5 us/step).
//    x_proj initial visibility = kernel-launch acquire; final out visibility
//    = kernel-end release. W/bias/x_proj stay warm in L1/L2 all 256 steps.
//  - W fragments pinned in VGPRs with a keep-alive INSIDE the t-loop (the
//    round-3 one-shot keep-alive failed: VGPR_Count=56 showed the 16 W loads
//    were sunk back into the loop).
//  - h_prev fp32 carried in registers (same thread produced it last step).
//  - Ping-pong hazard: barrier at step end guarantees all step-t h-reads
//    (which precede the epilogue) are done before any block writes parity
//    t&1 again at step t+1.
// ---------------------------------------------------------------------------
__global__ __launch_bounds__(256, 1) void rnn_persist(
    unsigned short* __restrict__ hT,            // ping-pong; parity0 = bf16(h0)
    const unsigned short* __restrict__ Wb,      // [1024][1024] bf16
    const float* __restrict__ b_hh,
    const float* __restrict__ h0,
    float* __restrict__ out)                    // [T][B][H]: in x_proj, out h_t
{
  __shared__ float red[2][16][17];   // [m-tile][b_local][j_local], +1 pad

  const int tid  = threadIdx.x;
  const int wv   = tid >> 6;
  const int lane = tid & 63;
  const int ln   = lane & 15;        // A: b-row / B: j-row / D: j-col
  const int q    = lane >> 4;        // 0..3

  const int jt = blockIdx.x & 63;
  const int bq = blockIdx.x >> 6;
  const int j0 = jt * 16;
  const int mt = wv & 1;             // m-tile within the 32-b quarter
  const int kh = wv >> 1;            // k-half
  const int b0 = bq * 32 + mt * 16;

  // W fragments: load once; keep-alive inside the t-loop pins them in VGPRs.
  const short8* __restrict__ wb8 =
      (const short8*)(Wb + (size_t)(j0 + ln) * H_DIM + kh * 512 + q * 8);
  short8 wfrag[16];
#pragma unroll
  for (int kc = 0; kc < 16; ++kc) wfrag[kc] = wb8[kc * 4];

  const size_t HT = (size_t)B_DIM * H_DIM;     // 131072
  const size_t arow = (size_t)(b0 + ln) * H_DIM + kh * 512 + q * 8;
  const unsigned short* __restrict__ ha0 = hT + arow;
  const unsigned short* __restrict__ ha1 = hT + HT + arow;

  const int jg = j0 + ln;
  const float bj  = b_hh[jg];
  const size_t obase = (size_t)(b0 + q * 4) * H_DIM + jg;   // epilogue base (wv<2)

  // fp32 h_prev carried in registers (this thread wrote the same (b,j) slots
  // last step). t=0 uses h0.
  float hcur[4];
  {
    const float h0j = h0[jg];
#pragma unroll
    for (int r = 0; r < 4; ++r) hcur[r] = h0j;
  }

  unsigned* bar = &g_bar[bq][0];

  for (int t = 0; t < T_LEN; ++t) {
    // Pin W in registers across the whole loop (asm "modifies" them each
    // iteration -> compiler cannot sink the loads back into the loop).
#pragma unroll
    for (int kc = 0; kc < 16; ++kc) asm volatile("" : "+v"(wfrag[kc]));

    float* __restrict__ xio_t = out + (size_t)t * HT;

    // Prefetch x_proj[t] (independent of h_{t-1}); L1/L2-warm after step 0's
    // HBM/L3 touch of this slice. Overlaps the h-load latency below.
    float xpv[4];
    if (wv < 2) {
#pragma unroll
      for (int r = 0; r < 4; ++r) xpv[r] = xio_t[obase + (size_t)r * H_DIM];
    }

    // h fragments: coherent L3 reads (sc0 sc1), 16 independent 16B loads,
    // one wait. No cache invalidate needed anywhere.
    const unsigned short* __restrict__ ha = (t & 1) ? ha1 : ha0;
    short8 hfrag[16];
#pragma unroll
    for (int kc = 0; kc < 16; ++kc) {
      asm volatile("global_load_dwordx4 %0, %1, off offset:%2 sc0 sc1"
                   : "=&v"(hfrag[kc]) : "v"(ha), "i"(kc * 64));
    }
    asm volatile("s_waitcnt vmcnt(0)" ::: "memory");
    __builtin_amdgcn_sched_barrier(0);   // rule #18: don't let MFMA hoist past

    f32x4 acc0 = {0.f, 0.f, 0.f, 0.f};
    f32x4 acc1 = {0.f, 0.f, 0.f, 0.f};
#pragma unroll
    for (int kc = 0; kc < 16; kc += 2) {   // two independent MFMA chains
      acc0 = __builtin_amdgcn_mfma_f32_16x16x32_bf16(hfrag[kc],     wfrag[kc],     acc0, 0, 0, 0);
      acc1 = __builtin_amdgcn_mfma_f32_16x16x32_bf16(hfrag[kc + 1], wfrag[kc + 1], acc1, 0, 0, 0);
    }
    const f32x4 acc = acc0 + acc1;

    // D layout: j_col = lane&15, b_row = (lane>>4)*4 + reg.
    if (wv >= 2) {
#pragma unroll
      for (int r = 0; r < 4; ++r) red[mt][q * 4 + r][ln] = acc[r];
    }
    __syncthreads();
    if (wv < 2) {
      unsigned short* __restrict__ hnext = hT + (size_t)((t + 1) & 1) * HT;
#pragma unroll
      for (int r = 0; r < 4; ++r) {
        const float rec = acc[r] + red[mt][q * 4 + r][ln];
        float v = 0.9f * hcur[r] + 0.1f * (rec + bj + xpv[r]);
        v = v > 0.f ? v : 0.f;
        hcur[r] = v;
        const size_t oidx = obase + (size_t)r * H_DIM;
        xio_t[oidx] = v;   // plain cached store; only re-read by this thread
        // h state: write-through (relaxed agent) -> visible at L3 once vmcnt
        // retires; the release fetch_add below covers any cached remainder.
        __hip_atomic_store(&hnext[oidx], f2bf(v), __ATOMIC_RELAXED,
                           __HIP_MEMORY_SCOPE_AGENT);
      }
    }
    __syncthreads();   // all waves' stores drained (vmcnt 0) before arrival
    if (tid == 0) {
      // Release arrival: flush dirty L2 + device-coherent add (r1/r3-proven).
      __hip_atomic_fetch_add(bar, 1u, __ATOMIC_RELEASE, __HIP_MEMORY_SCOPE_AGENT);
      const unsigned tgt = (unsigned)(t + 1) * 64u;
      // Spin with L1+L2-bypass loads: coherent and maintenance-free.
      unsigned cur;
      for (;;) {
        asm volatile("global_load_dword %0, %1, off sc0 sc1\n\t"
                     "s_waitcnt vmcnt(0)"
                     : "=v"(cur) : "v"(bar) : "memory");
        if (cur >= tgt) break;
        __builtin_amdgcn_s_sleep(2);
      }
      // NO acquire fence: h is read via sc0 sc1, counter via sc0 sc1 —
      // nothing stale can be observed through L1/L2.
    }
    __syncthreads();
  }
}

// ---------------------------------------------------------------------------
extern "C" void kernel_launch(void* const* d_in, const int* in_sizes, int n_in,
                              void* d_out, int out_size, void* d_ws, size_t ws_size,
                              hipStream_t stream) {
  const float* input = (const float*)d_in[0];
  const float* W_in  = (const float*)d_in[1];
  const float* b_in  = (const float*)d_in[2];
  const float* W_hh  = (const float*)d_in[3];
  const float* b_hh  = (const float*)d_in[4];
  const float* h0    = (const float*)d_in[5];
  float* out = (float*)d_out;

  // ws layout: [0, 2MB) Wb bf16 [1024][1024]; then hT ping-pong 2 x 256 KB.
  unsigned short* Wb = (unsigned short*)d_ws;
  unsigned short* hT = Wb + (1 << 20);

  cvt_w_bf16<<<(H_DIM * H_DIM / 4) / 256, 256, 0, stream>>>(W_hh, Wb);
  init_hT0<<<(B_DIM * H_DIM) / 256, 256, 0, stream>>>(h0, hT);

  dim3 g1(H_DIM / 64, (T_LEN * B_DIM) / 64);
  xproj_gemm<<<g1, 256, 0, stream>>>(input, W_in, b_in, out);

  {
    unsigned short* hT_ = hT;
    const unsigned short* Wb_ = Wb;
    const float* bhh_ = b_hh;
    const float* h0_ = h0;
    float* out_ = out;
    void* pargs[5] = {(void*)&hT_, (void*)&Wb_, (void*)&bhh_, (void*)&h0_, (void*)&out_};
    hipLaunchCooperativeKernel((const void*)rnn_persist, dim3(256), dim3(256),
                               pargs, 0, stream);
  }
}

// Round 5
// 1643.114 us; speedup vs baseline: 2.2625x; 2.2625x over previous
//
#include <hip/hip_runtime.h>
#include <hip/hip_bf16.h>

#define T_LEN 256
#define B_DIM 128
#define I_DIM 256
#define H_DIM 1024

typedef __attribute__((ext_vector_type(8))) short short8;
typedef __attribute__((ext_vector_type(4))) float f32x4;

// Sync words (re-zeroed by init_hT0 every call/replay).
// g_sync[bq*32 + lj]   : arrival flag of block lj in cluster bq (step value)
// g_sync[128 + bq*32]  : epoch word of cluster bq (clusters 128B apart)
__device__ unsigned g_sync[256];

// RNE float->bf16 (self-contained; inputs here are never NaN)
static __device__ __forceinline__ unsigned short f2bf(float f) {
  unsigned u = __float_as_uint(f);
  return (unsigned short)((u + 0x7fffu + ((u >> 16) & 1u)) >> 16);
}

// ---------------------------------------------------------------------------
// Phase 1: x_proj GEMM (fp32, unchanged).
// ---------------------------------------------------------------------------
__global__ __launch_bounds__(256) void xproj_gemm(
    const float* __restrict__ A, const float* __restrict__ W,
    const float* __restrict__ bias, float* __restrict__ C) {
  __shared__ float As[64][33];
  __shared__ float Ws[64][33];

  const int tid = threadIdx.x;
  const int m0 = blockIdx.y * 64;
  const int n0 = blockIdx.x * 64;
  const int ty = tid >> 4;
  const int tx = tid & 15;
  const int r   = tid >> 3;
  const int c4  = (tid & 7) << 2;

  float acc[4][4] = {};

  for (int kc = 0; kc < I_DIM; kc += 32) {
#pragma unroll
    for (int p = 0; p < 2; ++p) {
      const int rr = r + p * 32;
      const float4 a = *(const float4*)(A + (size_t)(m0 + rr) * I_DIM + kc + c4);
      As[rr][c4 + 0] = a.x; As[rr][c4 + 1] = a.y;
      As[rr][c4 + 2] = a.z; As[rr][c4 + 3] = a.w;
      const float4 w = *(const float4*)(W + (size_t)(n0 + rr) * I_DIM + kc + c4);
      Ws[rr][c4 + 0] = w.x; Ws[rr][c4 + 1] = w.y;
      Ws[rr][c4 + 2] = w.z; Ws[rr][c4 + 3] = w.w;
    }
    __syncthreads();
#pragma unroll
    for (int k = 0; k < 32; ++k) {
      float av[4], wv[4];
#pragma unroll
      for (int i = 0; i < 4; ++i) av[i] = As[ty * 4 + i][k];
#pragma unroll
      for (int j = 0; j < 4; ++j) wv[j] = Ws[tx * 4 + j][k];
#pragma unroll
      for (int i = 0; i < 4; ++i)
#pragma unroll
        for (int j = 0; j < 4; ++j)
          acc[i][j] = fmaf(av[i], wv[j], acc[i][j]);
    }
    __syncthreads();
  }

  const float4 bv = *(const float4*)(bias + n0 + tx * 4);
#pragma unroll
  for (int i = 0; i < 4; ++i) {
    float4 o;
    o.x = acc[i][0] + bv.x;
    o.y = acc[i][1] + bv.y;
    o.z = acc[i][2] + bv.z;
    o.w = acc[i][3] + bv.w;
    *(float4*)(C + (size_t)(m0 + ty * 4 + i) * H_DIM + n0 + tx * 4) = o;
  }
}

// ---------------------------------------------------------------------------
// One-time converts: W_hh -> bf16 [j][k]; hT0 -> bf16 [b][k] broadcast of h0.
// init_hT0 also re-zeroes the sync words.
// ---------------------------------------------------------------------------
__global__ __launch_bounds__(256) void cvt_w_bf16(
    const float* __restrict__ W, unsigned short* __restrict__ Wb) {
  const int i4 = blockIdx.x * 256 + threadIdx.x;     // one float4 per thread
  const float4 w = ((const float4*)W)[i4];
  ushort4 o;
  o.x = f2bf(w.x); o.y = f2bf(w.y); o.z = f2bf(w.z); o.w = f2bf(w.w);
  ((ushort4*)Wb)[i4] = o;
}

__global__ __launch_bounds__(256) void init_hT0(
    const float* __restrict__ h0, unsigned short* __restrict__ hT) {
  const int idx = blockIdx.x * 256 + threadIdx.x;    // [0, 131072)
  hT[idx] = f2bf(h0[idx & (H_DIM - 1)]);
  if (blockIdx.x == 0) g_sync[threadIdx.x] = 0u;
}

// ---------------------------------------------------------------------------
// Phase 2: persistent cooperative kernel — whole time loop in ONE dispatch.
// Grid 128 = 32 j-tiles (32 j each) x 4 b-quarter clusters. Block = 4 waves:
// wave w -> m-tile (w&1: 16 of the 32 b) x k-half (w>>1: 512 k).
//
// Round-5 change: the 64-RMW-per-line barrier (release fetch_add, all blocks
// of a cluster on ONE cache line) serialized at the L3 atomic unit — ~10 us
// of the 12.5 us step (r4: MfmaUtil 0.85%). Replaced by a ZERO-RMW
// flag/epoch barrier:
//   - arrival: each block WT-stores t+1 into its OWN flag word
//   - leader block's wave 0: wave-parallel sc0sc1 poll of all 32 flags
//     (+ __all), then WT-stores epoch = t+1
//   - followers: tid0 polls the epoch word (sc0sc1)
// Ordering: flag stored after __syncthreads drained all waves' WT data
// stores (already at coherence point); epoch only after leader saw all
// flags; h read via sc0sc1 -> always fresh. No RMW, no cache maintenance.
// Cluster shrunk 64->32 blocks: halves arrivals and the redundant h burst.
//
// Data paths kept from r4 (all proven): h stores WT relaxed-agent atomics;
// h loads inline-asm sc0 sc1 (L1/L2-bypass, coherent at L3); W pinned in
// VGPRs (keep-alive inside the loop); fp32 h_prev carried in registers;
// xio / W / bias plain cached (no per-step invalidate anywhere).
// ---------------------------------------------------------------------------
__global__ __launch_bounds__(256, 1) void rnn_persist(
    unsigned short* __restrict__ hT,            // ping-pong; parity0 = bf16(h0)
    const unsigned short* __restrict__ Wb,      // [1024][1024] bf16
    const float* __restrict__ b_hh,
    const float* __restrict__ h0,
    float* __restrict__ out)                    // [T][B][H]: in x_proj, out h_t
{
  __shared__ float red[2][16][33];   // [m-tile][b_local][j_local 0..31], +pad

  const int tid  = threadIdx.x;
  const int wv   = tid >> 6;
  const int lane = tid & 63;
  const int ln   = lane & 15;        // A: b-row / B: j-row / D: j-col
  const int q    = lane >> 4;        // 0..3

  const int bid = blockIdx.x;
  const int bq  = bid >> 5;          // cluster (batch quarter)
  const int lj  = bid & 31;          // j-tile within cluster
  const int j0  = lj * 32;
  const int mt  = wv & 1;            // m-tile within the 32-b quarter
  const int kh  = wv >> 1;           // k-half
  const int b0  = bq * 32 + mt * 16;

  // W fragments: 2 j-subtiles x 16 k-chunks = 32 short8 = 128 VGPRs.
  // Loaded once (dispatch-boundary flush makes cvt output visible); pinned
  // by an in-loop keep-alive.
  short8 wfrag[2][16];
#pragma unroll
  for (int jf = 0; jf < 2; ++jf) {
    const short8* __restrict__ wb8 =
        (const short8*)(Wb + (size_t)(j0 + jf * 16 + ln) * H_DIM + kh * 512 + q * 8);
#pragma unroll
    for (int kc = 0; kc < 16; ++kc) wfrag[jf][kc] = wb8[kc * 4];
  }

  const size_t HT = (size_t)B_DIM * H_DIM;     // 131072
  const size_t arow = (size_t)(b0 + ln) * H_DIM + kh * 512 + q * 8;
  const unsigned short* __restrict__ ha0 = hT + arow;
  const unsigned short* __restrict__ ha1 = hT + HT + arow;

  float bj[2];
#pragma unroll
  for (int jf = 0; jf < 2; ++jf) bj[jf] = b_hh[j0 + jf * 16 + ln];

  // Epilogue (wv<2) output base: row = b0 + q*4 (+r), col = j0 + jf*16 + ln.
  const size_t obase = (size_t)(b0 + q * 4) * H_DIM + j0 + ln;

  // fp32 h_prev carried in registers; t=0 uses h0.
  float hcur[2][4];
#pragma unroll
  for (int jf = 0; jf < 2; ++jf) {
    const float h0j = h0[j0 + jf * 16 + ln];
#pragma unroll
    for (int r = 0; r < 4; ++r) hcur[jf][r] = h0j;
  }

  unsigned* flags = &g_sync[bq * 32];
  unsigned* epoch = &g_sync[128 + bq * 32];

  for (int t = 0; t < T_LEN; ++t) {
    // Pin W in registers (asm "modifies" them each iteration -> compiler
    // cannot sink the loads into the loop or spill them).
#pragma unroll
    for (int jf = 0; jf < 2; ++jf)
#pragma unroll
      for (int kc = 0; kc < 16; ++kc) asm volatile("" : "+v"(wfrag[jf][kc]));

    float* __restrict__ xio_t = out + (size_t)t * HT;

    // Prefetch x_proj[t] (independent of h_{t-1}); overlaps h-load latency.
    float xpv[2][4];
    if (wv < 2) {
#pragma unroll
      for (int jf = 0; jf < 2; ++jf)
#pragma unroll
        for (int r = 0; r < 4; ++r)
          xpv[jf][r] = xio_t[obase + (size_t)r * H_DIM + jf * 16];
    }

    // h fragments: coherent L3 reads (sc0 sc1), 16 independent 16B loads.
    const unsigned short* __restrict__ ha = (t & 1) ? ha1 : ha0;
    short8 hfrag[16];
#pragma unroll
    for (int kc = 0; kc < 16; ++kc) {
      asm volatile("global_load_dwordx4 %0, %1, off offset:%2 sc0 sc1"
                   : "=&v"(hfrag[kc]) : "v"(ha), "i"(kc * 64));
    }
    asm volatile("s_waitcnt vmcnt(0)" ::: "memory");
    __builtin_amdgcn_sched_barrier(0);   // rule #18

    // 4 independent MFMA chains (2 j-subtiles x 2 accumulators).
    f32x4 a0[2], a1[2];
#pragma unroll
    for (int jf = 0; jf < 2; ++jf) { a0[jf] = (f32x4){0,0,0,0}; a1[jf] = (f32x4){0,0,0,0}; }
#pragma unroll
    for (int kc = 0; kc < 16; kc += 2) {
#pragma unroll
      for (int jf = 0; jf < 2; ++jf) {
        a0[jf] = __builtin_amdgcn_mfma_f32_16x16x32_bf16(hfrag[kc],     wfrag[jf][kc],     a0[jf], 0, 0, 0);
        a1[jf] = __builtin_amdgcn_mfma_f32_16x16x32_bf16(hfrag[kc + 1], wfrag[jf][kc + 1], a1[jf], 0, 0, 0);
      }
    }
    f32x4 acc[2];
#pragma unroll
    for (int jf = 0; jf < 2; ++jf) acc[jf] = a0[jf] + a1[jf];

    // D layout: j_col = lane&15, b_row = (lane>>4)*4 + reg.
    if (wv >= 2) {
#pragma unroll
      for (int jf = 0; jf < 2; ++jf)
#pragma unroll
        for (int r = 0; r < 4; ++r) red[mt][q * 4 + r][jf * 16 + ln] = acc[jf][r];
    }
    __syncthreads();
    if (wv < 2) {
      unsigned short* __restrict__ hnext = hT + (size_t)((t + 1) & 1) * HT;
#pragma unroll
      for (int jf = 0; jf < 2; ++jf)
#pragma unroll
        for (int r = 0; r < 4; ++r) {
          const float rec = acc[jf][r] + red[mt][q * 4 + r][jf * 16 + ln];
          float v = 0.9f * hcur[jf][r] + 0.1f * (rec + bj[jf] + xpv[jf][r]);
          v = v > 0.f ? v : 0.f;
          hcur[jf][r] = v;
          const size_t oidx = obase + (size_t)r * H_DIM + jf * 16;
          xio_t[oidx] = v;   // plain cached; only this thread re-reads it
          // h state: write-through relaxed-agent -> at L3 once vmcnt retires.
          __hip_atomic_store(&hnext[oidx], f2bf(v), __ATOMIC_RELAXED,
                             __HIP_MEMORY_SCOPE_AGENT);
        }
    }
    __syncthreads();   // all waves' WT stores drained (vmcnt 0) before flag

    // ---- zero-RMW cluster barrier ----
    const unsigned tgt = (unsigned)(t + 1);
    if (lj == 0) {
      if (wv == 0) {                      // leader: wave-parallel flag poll
        if (lane == 0)
          __hip_atomic_store(&flags[0], tgt, __ATOMIC_RELAXED,
                             __HIP_MEMORY_SCOPE_AGENT);
        unsigned* fp = &flags[lane & 31]; // lanes 32-63 duplicate 0-31
        for (;;) {
          unsigned fv;
          asm volatile("global_load_dword %0, %1, off sc0 sc1\n\t"
                       "s_waitcnt vmcnt(0)"
                       : "=v"(fv) : "v"(fp) : "memory");
          if (__all((int)fv >= (int)tgt)) break;
          __builtin_amdgcn_s_sleep(1);
        }
        if (lane == 0)
          __hip_atomic_store(epoch, tgt, __ATOMIC_RELAXED,
                             __HIP_MEMORY_SCOPE_AGENT);
      }
    } else if (tid == 0) {                // follower: arrive, poll epoch
      __hip_atomic_store(&flags[lj], tgt, __ATOMIC_RELAXED,
                         __HIP_MEMORY_SCOPE_AGENT);
      for (;;) {
        unsigned ev;
        asm volatile("global_load_dword %0, %1, off sc0 sc1\n\t"
                     "s_waitcnt vmcnt(0)"
                     : "=v"(ev) : "v"(epoch) : "memory");
        if (ev >= tgt) break;
        __builtin_amdgcn_s_sleep(1);
      }
    }
    __syncthreads();
  }
}

// ---------------------------------------------------------------------------
extern "C" void kernel_launch(void* const* d_in, const int* in_sizes, int n_in,
                              void* d_out, int out_size, void* d_ws, size_t ws_size,
                              hipStream_t stream) {
  const float* input = (const float*)d_in[0];
  const float* W_in  = (const float*)d_in[1];
  const float* b_in  = (const float*)d_in[2];
  const float* W_hh  = (const float*)d_in[3];
  const float* b_hh  = (const float*)d_in[4];
  const float* h0    = (const float*)d_in[5];
  float* out = (float*)d_out;

  // ws layout: [0, 2MB) Wb bf16 [1024][1024]; then hT ping-pong 2 x 256 KB.
  unsigned short* Wb = (unsigned short*)d_ws;
  unsigned short* hT = Wb + (1 << 20);

  cvt_w_bf16<<<(H_DIM * H_DIM / 4) / 256, 256, 0, stream>>>(W_hh, Wb);
  init_hT0<<<(B_DIM * H_DIM) / 256, 256, 0, stream>>>(h0, hT);

  dim3 g1(H_DIM / 64, (T_LEN * B_DIM) / 64);
  xproj_gemm<<<g1, 256, 0, stream>>>(input, W_in, b_in, out);

  {
    unsigned short* hT_ = hT;
    const unsigned short* Wb_ = Wb;
    const float* bhh_ = b_hh;
    const float* h0_ = h0;
    float* out_ = out;
    void* pargs[5] = {(void*)&hT_, (void*)&Wb_, (void*)&bhh_, (void*)&h0_, (void*)&out_};
    hipLaunchCooperativeKernel((const void*)rnn_persist, dim3(128), dim3(256),
                               pargs, 0, stream);
  }
}

// Round 6
// 1552.035 us; speedup vs baseline: 2.3952x; 1.0587x over previous
//
#include <hip/hip_runtime.h>
#include <hip/hip_bf16.h>

#define T_LEN 256
#define B_DIM 128
#define I_DIM 256
#define H_DIM 1024

typedef __attribute__((ext_vector_type(8))) short short8;
typedef __attribute__((ext_vector_type(4))) float f32x4;

// Per-cluster arrival flags (monotonic step counts). g_sync[bq*32 + lj].
// Re-zeroed by init_hT0 every call/replay.
__device__ unsigned g_sync[256];

// RNE float->bf16 (self-contained; inputs here are never NaN)
static __device__ __forceinline__ unsigned short f2bf(float f) {
  unsigned u = __float_as_uint(f);
  return (unsigned short)((u + 0x7fffu + ((u >> 16) & 1u)) >> 16);
}
static __device__ __forceinline__ float bf2f(unsigned short h) {
  return __uint_as_float((unsigned)h << 16);
}

// ---------------------------------------------------------------------------
// Phase 1a (fallback): x_proj GEMM fp32 (proven, used when ws is small).
// ---------------------------------------------------------------------------
__global__ __launch_bounds__(256) void xproj_gemm(
    const float* __restrict__ A, const float* __restrict__ W,
    const float* __restrict__ bias, float* __restrict__ C) {
  __shared__ float As[64][33];
  __shared__ float Ws[64][33];

  const int tid = threadIdx.x;
  const int m0 = blockIdx.y * 64;
  const int n0 = blockIdx.x * 64;
  const int ty = tid >> 4;
  const int tx = tid & 15;
  const int r   = tid >> 3;
  const int c4  = (tid & 7) << 2;

  float acc[4][4] = {};

  for (int kc = 0; kc < I_DIM; kc += 32) {
#pragma unroll
    for (int p = 0; p < 2; ++p) {
      const int rr = r + p * 32;
      const float4 a = *(const float4*)(A + (size_t)(m0 + rr) * I_DIM + kc + c4);
      As[rr][c4 + 0] = a.x; As[rr][c4 + 1] = a.y;
      As[rr][c4 + 2] = a.z; As[rr][c4 + 3] = a.w;
      const float4 w = *(const float4*)(W + (size_t)(n0 + rr) * I_DIM + kc + c4);
      Ws[rr][c4 + 0] = w.x; Ws[rr][c4 + 1] = w.y;
      Ws[rr][c4 + 2] = w.z; Ws[rr][c4 + 3] = w.w;
    }
    __syncthreads();
#pragma unroll
    for (int k = 0; k < 32; ++k) {
      float av[4], wv[4];
#pragma unroll
      for (int i = 0; i < 4; ++i) av[i] = As[ty * 4 + i][k];
#pragma unroll
      for (int j = 0; j < 4; ++j) wv[j] = Ws[tx * 4 + j][k];
#pragma unroll
      for (int i = 0; i < 4; ++i)
#pragma unroll
        for (int j = 0; j < 4; ++j)
          acc[i][j] = fmaf(av[i], wv[j], acc[i][j]);
    }
    __syncthreads();
  }

  const float4 bv = *(const float4*)(bias + n0 + tx * 4);
#pragma unroll
  for (int i = 0; i < 4; ++i) {
    float4 o;
    o.x = acc[i][0] + bv.x;
    o.y = acc[i][1] + bv.y;
    o.z = acc[i][2] + bv.z;
    o.w = acc[i][3] + bv.w;
    *(float4*)(C + (size_t)(m0 + ty * 4 + i) * H_DIM + n0 + tx * 4) = o;
  }
}

// ---------------------------------------------------------------------------
// Phase 1b: x_proj via split-bf16 MFMA.
//   a = ah + al (ah = bf16(a), al = bf16(a-ah); |a-ah-al| ~ 2^-17 |a|)
//   C = Ah·Wh^T + Ah·Wl^T + Al·Wh^T   (al·wl term ~2^-18, dropped)
// fp32-grade accuracy at bf16-MFMA speed. Block 256 thr = 4 waves (2m x 2n);
// tile 128(M) x 64(N); fragments loaded directly from global (L2-resident).
// ---------------------------------------------------------------------------
__global__ __launch_bounds__(256) void cvt_hi_lo(
    const float* __restrict__ X, unsigned short* __restrict__ Xh,
    unsigned short* __restrict__ Xl) {
  const int i4 = blockIdx.x * 256 + threadIdx.x;     // one float4 per thread
  const float4 x = ((const float4*)X)[i4];
  ushort4 h, l;
  h.x = f2bf(x.x); l.x = f2bf(x.x - bf2f(h.x));
  h.y = f2bf(x.y); l.y = f2bf(x.y - bf2f(h.y));
  h.z = f2bf(x.z); l.z = f2bf(x.z - bf2f(h.z));
  h.w = f2bf(x.w); l.w = f2bf(x.w - bf2f(h.w));
  ((ushort4*)Xh)[i4] = h;
  ((ushort4*)Xl)[i4] = l;
}

__global__ __launch_bounds__(256) void xproj_mfma(
    const unsigned short* __restrict__ Ah, const unsigned short* __restrict__ Al,
    const unsigned short* __restrict__ Wh, const unsigned short* __restrict__ Wl,
    const float* __restrict__ bias, float* __restrict__ C) {
  const int tid  = threadIdx.x;
  const int wv   = tid >> 6;
  const int lane = tid & 63;
  const int ln   = lane & 15;
  const int q    = lane >> 4;
  const int mw   = wv >> 1;                 // 0..1
  const int nw   = wv & 1;                  // 0..1
  const int m0   = blockIdx.y * 128 + mw * 64;
  const int n0   = blockIdx.x * 64  + nw * 32;

  f32x4 acc[4][2] = {};

#pragma unroll
  for (int kc = 0; kc < 8; ++kc) {          // K = 256 = 8 x 32
    const int ko = kc * 32 + q * 8;
    short8 afh[4], afl[4], wfh[2], wfl[2];
#pragma unroll
    for (int fm = 0; fm < 4; ++fm) {
      const size_t off = (size_t)(m0 + fm * 16 + ln) * I_DIM + ko;
      afh[fm] = *(const short8*)(Ah + off);
      afl[fm] = *(const short8*)(Al + off);
    }
#pragma unroll
    for (int fn = 0; fn < 2; ++fn) {
      const size_t off = (size_t)(n0 + fn * 16 + ln) * I_DIM + ko;
      wfh[fn] = *(const short8*)(Wh + off);
      wfl[fn] = *(const short8*)(Wl + off);
    }
#pragma unroll
    for (int fm = 0; fm < 4; ++fm)
#pragma unroll
      for (int fn = 0; fn < 2; ++fn) {
        acc[fm][fn] = __builtin_amdgcn_mfma_f32_16x16x32_bf16(afh[fm], wfh[fn], acc[fm][fn], 0, 0, 0);
        acc[fm][fn] = __builtin_amdgcn_mfma_f32_16x16x32_bf16(afh[fm], wfl[fn], acc[fm][fn], 0, 0, 0);
        acc[fm][fn] = __builtin_amdgcn_mfma_f32_16x16x32_bf16(afl[fm], wfh[fn], acc[fm][fn], 0, 0, 0);
      }
  }

  // D layout: col (j) = lane&15, row (m) = (lane>>4)*4 + reg.
#pragma unroll
  for (int fn = 0; fn < 2; ++fn) {
    const int j = n0 + fn * 16 + ln;
    const float bj = bias[j];
#pragma unroll
    for (int fm = 0; fm < 4; ++fm)
#pragma unroll
      for (int r = 0; r < 4; ++r)
        C[(size_t)(m0 + fm * 16 + q * 4 + r) * H_DIM + j] = acc[fm][fn][r] + bj;
  }
}

// ---------------------------------------------------------------------------
// One-time converts: W_hh -> bf16 [j][k]; hT0 -> bf16 broadcast of h0.
// init_hT0 also re-zeroes the sync flags.
// ---------------------------------------------------------------------------
__global__ __launch_bounds__(256) void cvt_w_bf16(
    const float* __restrict__ W, unsigned short* __restrict__ Wb) {
  const int i4 = blockIdx.x * 256 + threadIdx.x;
  const float4 w = ((const float4*)W)[i4];
  ushort4 o;
  o.x = f2bf(w.x); o.y = f2bf(w.y); o.z = f2bf(w.z); o.w = f2bf(w.w);
  ((ushort4*)Wb)[i4] = o;
}

__global__ __launch_bounds__(256) void init_hT0(
    const float* __restrict__ h0, unsigned short* __restrict__ hT) {
  const int idx = blockIdx.x * 256 + threadIdx.x;    // [0, 131072)
  hT[idx] = f2bf(h0[idx & (H_DIM - 1)]);
  if (blockIdx.x == 0) g_sync[threadIdx.x] = 0u;
}

// ---------------------------------------------------------------------------
// Phase 2: persistent cooperative kernel — whole time loop in ONE dispatch.
// Grid 128 = 32 j-tiles (32 j) x 4 b-quarter clusters. Block = 4 waves:
// wave w -> m-tile (w&1) x k-half (w>>1).
//
// Round-6 barrier: single-stage per-k-half producer polling (r5's two-stage
// leader/epoch chain cost ~2 extra L3 round-trips/step).
//  - end of step t: after __syncthreads drains all WT h-stores, tid0
//    WT-stores flag = t+1 into this block's OWN word.
//  - start of step t: each wave polls ONLY its 16 k-half producers
//    (lanes parallel, sc0sc1 loads, __all), then loads its h fragments.
//  - ping-pong overwrite safety: the epilogue sits after a __syncthreads
//    joining all 4 waves, whose polls cover the UNION of all 32 cluster
//    blocks  ->  a block can only overwrite parity p once every cluster
//    block has signaled completion of the step that last read p.
// Data paths (proven r4/r5): h stores WT relaxed-agent; h loads inline-asm
// sc0 sc1 (coherent at L3, no cache maintenance anywhere); W pinned in VGPRs
// (in-loop keep-alive); fp32 h_prev carried in registers.
// ---------------------------------------------------------------------------
__global__ __launch_bounds__(256, 1) void rnn_persist(
    unsigned short* __restrict__ hT,            // ping-pong; parity0 = bf16(h0)
    const unsigned short* __restrict__ Wb,      // [1024][1024] bf16
    const float* __restrict__ b_hh,
    const float* __restrict__ h0,
    float* __restrict__ out)                    // [T][B][H]: in x_proj, out h_t
{
  __shared__ float red[2][16][33];   // [m-tile][b_local][j_local 0..31], +pad

  const int tid  = threadIdx.x;
  const int wv   = tid >> 6;
  const int lane = tid & 63;
  const int ln   = lane & 15;        // A: b-row / B: j-row / D: j-col
  const int q    = lane >> 4;        // 0..3

  const int bid = blockIdx.x;
  const int bq  = bid >> 5;          // cluster (batch quarter)
  const int lj  = bid & 31;          // j-tile within cluster
  const int j0  = lj * 32;
  const int mt  = wv & 1;            // m-tile within the 32-b quarter
  const int kh  = wv >> 1;           // k-half
  const int b0  = bq * 32 + mt * 16;

  // W fragments: 2 j-subtiles x 16 k-chunks = 32 short8 = 128 VGPRs.
  short8 wfrag[2][16];
#pragma unroll
  for (int jf = 0; jf < 2; ++jf) {
    const short8* __restrict__ wb8 =
        (const short8*)(Wb + (size_t)(j0 + jf * 16 + ln) * H_DIM + kh * 512 + q * 8);
#pragma unroll
    for (int kc = 0; kc < 16; ++kc) wfrag[jf][kc] = wb8[kc * 4];
  }

  const size_t HT = (size_t)B_DIM * H_DIM;     // 131072
  const size_t arow = (size_t)(b0 + ln) * H_DIM + kh * 512 + q * 8;
  const unsigned short* __restrict__ ha0 = hT + arow;
  const unsigned short* __restrict__ ha1 = hT + HT + arow;

  float bj[2];
#pragma unroll
  for (int jf = 0; jf < 2; ++jf) bj[jf] = b_hh[j0 + jf * 16 + ln];

  const size_t obase = (size_t)(b0 + q * 4) * H_DIM + j0 + ln;

  float hcur[2][4];
#pragma unroll
  for (int jf = 0; jf < 2; ++jf) {
    const float h0j = h0[j0 + jf * 16 + ln];
#pragma unroll
    for (int r = 0; r < 4; ++r) hcur[jf][r] = h0j;
  }

  unsigned* flags = &g_sync[bq * 32];
  unsigned* myflag = &g_sync[bq * 32 + lj];
  unsigned* pollp  = &g_sync[bq * 32 + kh * 16 + ln];  // this wave's producer

  for (int t = 0; t < T_LEN; ++t) {
    // Pin W in registers (asm "modifies" them each iteration).
#pragma unroll
    for (int jf = 0; jf < 2; ++jf)
#pragma unroll
      for (int kc = 0; kc < 16; ++kc) asm volatile("" : "+v"(wfrag[jf][kc]));

    float* __restrict__ xio_t = out + (size_t)t * HT;

    // Prefetch x_proj[t] (own slice; nobody else writes it).
    float xpv[2][4];
    if (wv < 2) {
#pragma unroll
      for (int jf = 0; jf < 2; ++jf)
#pragma unroll
        for (int r = 0; r < 4; ++r)
          xpv[jf][r] = xio_t[obase + (size_t)r * H_DIM + jf * 16];
    }

    // ---- single-stage poll: wait for this wave's 16 k-half producers ----
    if (t > 0) {
      const unsigned tgt = (unsigned)t;
      for (;;) {
        unsigned fv;
        asm volatile("global_load_dword %0, %1, off sc0 sc1\n\t"
                     "s_waitcnt vmcnt(0)"
                     : "=v"(fv) : "v"(pollp) : "memory");
        if (__all((int)fv >= (int)tgt)) break;
        __builtin_amdgcn_s_sleep(1);
      }
    }
    __builtin_amdgcn_sched_barrier(0);

    // h fragments: coherent L3 reads (sc0 sc1), 16 independent 16B loads.
    const unsigned short* __restrict__ ha = (t & 1) ? ha1 : ha0;
    short8 hfrag[16];
#pragma unroll
    for (int kc = 0; kc < 16; ++kc) {
      asm volatile("global_load_dwordx4 %0, %1, off offset:%2 sc0 sc1"
                   : "=&v"(hfrag[kc]) : "v"(ha), "i"(kc * 64));
    }
    asm volatile("s_waitcnt vmcnt(0)" ::: "memory");
    __builtin_amdgcn_sched_barrier(0);   // rule #18

    // 4 independent MFMA chains (2 j-subtiles x 2 accumulators).
    f32x4 a0[2], a1[2];
#pragma unroll
    for (int jf = 0; jf < 2; ++jf) { a0[jf] = (f32x4){0,0,0,0}; a1[jf] = (f32x4){0,0,0,0}; }
#pragma unroll
    for (int kc = 0; kc < 16; kc += 2) {
#pragma unroll
      for (int jf = 0; jf < 2; ++jf) {
        a0[jf] = __builtin_amdgcn_mfma_f32_16x16x32_bf16(hfrag[kc],     wfrag[jf][kc],     a0[jf], 0, 0, 0);
        a1[jf] = __builtin_amdgcn_mfma_f32_16x16x32_bf16(hfrag[kc + 1], wfrag[jf][kc + 1], a1[jf], 0, 0, 0);
      }
    }
    f32x4 acc[2];
#pragma unroll
    for (int jf = 0; jf < 2; ++jf) acc[jf] = a0[jf] + a1[jf];

    // D layout: j_col = lane&15, b_row = (lane>>4)*4 + reg.
    if (wv >= 2) {
#pragma unroll
      for (int jf = 0; jf < 2; ++jf)
#pragma unroll
        for (int r = 0; r < 4; ++r) red[mt][q * 4 + r][jf * 16 + ln] = acc[jf][r];
    }
    __syncthreads();   // joins all 4 waves => all 32 producer flags >= t seen
    if (wv < 2) {
      unsigned short* __restrict__ hnext = hT + (size_t)((t + 1) & 1) * HT;
#pragma unroll
      for (int jf = 0; jf < 2; ++jf)
#pragma unroll
        for (int r = 0; r < 4; ++r) {
          const float rec = acc[jf][r] + red[mt][q * 4 + r][jf * 16 + ln];
          float v = 0.9f * hcur[jf][r] + 0.1f * (rec + bj[jf] + xpv[jf][r]);
          v = v > 0.f ? v : 0.f;
          hcur[jf][r] = v;
          const size_t oidx = obase + (size_t)r * H_DIM + jf * 16;
          xio_t[oidx] = v;   // plain cached; only this thread re-reads it
          __hip_atomic_store(&hnext[oidx], f2bf(v), __ATOMIC_RELAXED,
                             __HIP_MEMORY_SCOPE_AGENT);
        }
    }
    __syncthreads();   // drains epilogue WT stores (vmcnt 0) before flag
    if (tid == 0)
      __hip_atomic_store(myflag, (unsigned)(t + 1), __ATOMIC_RELAXED,
                         __HIP_MEMORY_SCOPE_AGENT);
  }
  (void)flags;
}

// ---------------------------------------------------------------------------
extern "C" void kernel_launch(void* const* d_in, const int* in_sizes, int n_in,
                              void* d_out, int out_size, void* d_ws, size_t ws_size,
                              hipStream_t stream) {
  const float* input = (const float*)d_in[0];
  const float* W_in  = (const float*)d_in[1];
  const float* b_in  = (const float*)d_in[2];
  const float* W_hh  = (const float*)d_in[3];
  const float* b_hh  = (const float*)d_in[4];
  const float* h0    = (const float*)d_in[5];
  float* out = (float*)d_out;

  // ws layout (bytes):
  //   [0,  2M)  Wb    bf16 [1024][1024]
  //   [2M, 2.5M) hT   ping-pong 2 x 256 KB
  //   [2.5M,3M) Wih   bf16-hi W_in [1024][256]
  //   [3M, 3.5M) Wil  bf16-lo
  //   [4M, 20M) Ah    bf16-hi input [32768][256]
  //   [20M,36M) Al    bf16-lo
  char* ws = (char*)d_ws;
  unsigned short* Wb  = (unsigned short*)ws;
  unsigned short* hT  = (unsigned short*)(ws + (2u << 20));
  unsigned short* Wih = (unsigned short*)(ws + (5u << 19));   // 2.5 MB
  unsigned short* Wil = (unsigned short*)(ws + (3u << 20));
  unsigned short* Ah  = (unsigned short*)(ws + (4u << 20));
  unsigned short* Al  = (unsigned short*)(ws + (20u << 20));

  cvt_w_bf16<<<(H_DIM * H_DIM / 4) / 256, 256, 0, stream>>>(W_hh, Wb);
  init_hT0<<<(B_DIM * H_DIM) / 256, 256, 0, stream>>>(h0, hT);

  if (ws_size >= (36u << 20)) {
    // split-bf16 MFMA x_proj (fp32-grade accuracy)
    cvt_hi_lo<<<(T_LEN * B_DIM * I_DIM / 4) / 256, 256, 0, stream>>>(input, Ah, Al);
    cvt_hi_lo<<<(H_DIM * I_DIM / 4) / 256, 256, 0, stream>>>(W_in, Wih, Wil);
    dim3 g1(H_DIM / 64, (T_LEN * B_DIM) / 128);
    xproj_mfma<<<g1, 256, 0, stream>>>(Ah, Al, Wih, Wil, b_in, out);
  } else {
    dim3 g1(H_DIM / 64, (T_LEN * B_DIM) / 64);
    xproj_gemm<<<g1, 256, 0, stream>>>(input, W_in, b_in, out);
  }

  {
    unsigned short* hT_ = hT;
    const unsigned short* Wb_ = Wb;
    const float* bhh_ = b_hh;
    const float* h0_ = h0;
    float* out_ = out;
    void* pargs[5] = {(void*)&hT_, (void*)&Wb_, (void*)&bhh_, (void*)&h0_, (void*)&out_};
    hipLaunchCooperativeKernel((const void*)rnn_persist, dim3(128), dim3(256),
                               pargs, 0, stream);
  }
}